// Round 10
// baseline (668.924 us; speedup 1.0000x reference)
//
#include <hip/hip_runtime.h>

// Trilinear sampling of tsdf/weights volumes at M = B*H*N points.
// D = 256 fixed (reference). Outputs concatenated flat in d_out as float32:
//   [0,        M)   fusion_values
//   [M,      25M)   indices  (M,8,3) -- stored as float-valued integers
//   [25M,    33M)   weights  (M,8)
//   [33M,    34M)   fusion_weights
//
// v8 (resubmit; round-9 bench died to a container failure, not the kernel):
//   v7 (brick layout + LDS-coalesced stores, extractor ~237us) with the
//   gather path restructured for memory-level parallelism:
//     phase A: all 8 packed-offsets computed; idx floats written straight
//              to LDS (frees the 24-reg idxf array);
//     phase B: 8 v2f gathers issued back-to-back (batched in flight);
//     phase C: accumulate with a validity bitmask.
//   Rationale: VGPR_Count=28 in v4/v7 shows the compiler serialized the
//   gathers (~3-4 in flight). v6's batching attempt was confounded by a
//   store-stride regression and never raised VGPR. Keep VGPR < 64 so
//   occupancy stays at the LDS cap (6 blocks/CU, 75%).

typedef float v2f __attribute__((ext_vector_type(2)));
typedef float v4f __attribute__((ext_vector_type(4)));

// ---------------- pack: 2x2x2 bricks, one thread per brick -----------------
__global__ __launch_bounds__(256) void pack_brick_kernel(
    const float* __restrict__ tsdf,
    const float* __restrict__ wvol,
    float* __restrict__ packed)      // 128^3 bricks * 16 floats
{
    const int t = blockIdx.x * 256 + threadIdx.x;
    const int bz = t & 127;
    const int by = (t >> 7) & 127;
    const int bx = t >> 14;
    const int x0 = bx << 1, y0 = by << 1, z0 = bz << 1;

    v4f o[4];
#pragma unroll
    for (int dx = 0; dx < 2; ++dx) {
#pragma unroll
        for (int dy = 0; dy < 2; ++dy) {
            const size_t src = ((size_t)(x0 + dx) << 16) |
                               (size_t)((y0 + dy) << 8) | (size_t)z0;
            const v2f tp = *reinterpret_cast<const v2f*>(tsdf + src);
            const v2f wp = *reinterpret_cast<const v2f*>(wvol + src);
            v4f o4; o4.x = tp.x; o4.y = wp.x; o4.z = tp.y; o4.w = wp.y;
            o[dx * 2 + dy] = o4;
        }
    }
    v4f* __restrict__ dst = reinterpret_cast<v4f*>(packed + ((size_t)t << 4));
    dst[0] = o[0];
    dst[1] = o[1];
    dst[2] = o[2];
    dst[3] = o[3];
}

// ---------------- v8 extractor: batched gathers + LDS-coalesced stores -----
// Requires M % 256 == 0 (host checks; true for the reference shape).
__global__ __launch_bounds__(256) void extractor_lds(
    const float* __restrict__ points,
    const float* __restrict__ packed,
    float* __restrict__ out,
    int M)
{
    __shared__ v4f s4[256 * 6];      // 24 KB; idx phase uses 1536, wts 512
    float* __restrict__ sf = reinterpret_cast<float*>(s4);

    const int tid = threadIdx.x;
    const int m = blockIdx.x * 256 + tid;

    const size_t p3 = 3ull * (size_t)m;
    const float px = points[p3 + 0];
    const float py = points[p3 + 1];
    const float pz = points[p3 + 2];

    const float fx = floorf(px), fy = floorf(py), fz = floorf(pz);
    const int bx = (int)fx, by = (int)fy, bz = (int)fz;

    const float dxc = fx + 0.5f - px;
    const float dyc = fy + 0.5f - py;
    const float dzc = fz + 0.5f - pz;

    const int nx = (dxc > 0.f) ? 1 : ((dxc < 0.f) ? -1 : 0);
    const int ny = (dyc > 0.f) ? 1 : ((dyc < 0.f) ? -1 : 0);
    const int nz = (dzc > 0.f) ? 1 : ((dzc < 0.f) ? -1 : 0);

    const float ax = fabsf(dxc), ay = fabsf(dyc), az = fabsf(dzc);
    const float axi = 1.f - ax, ayi = 1.f - ay, azi = 1.f - az;

    // ---- phase A: offsets + validity + weights; idx straight to LDS ----
    int offs[8];
    float wts[8];
    unsigned vmask = 0u;
#pragma unroll
    for (int c = 0; c < 8; ++c) {
        const int ox = (c >> 2) & 1;
        const int oy = (c >> 1) & 1;
        const int oz = c & 1;
        const int cx = bx + (ox ? nx : 0);
        const int cy = by + (oy ? ny : 0);
        const int cz = bz + (oz ? nz : 0);
        const float w = (ox ? ax : axi) * (oy ? ay : ayi) * (oz ? az : azi);
        const bool valid = ((unsigned)cx < 256u) & ((unsigned)cy < 256u) & ((unsigned)cz < 256u);
        vmask |= (valid ? 1u : 0u) << c;
        const int ccx = min(max(cx, 0), 255);
        const int ccy = min(max(cy, 0), 255);
        const int ccz = min(max(cz, 0), 255);
        const int brick = ((ccx >> 1) << 14) | ((ccy >> 1) << 7) | (ccz >> 1);
        const int off = ((ccx & 1) << 2) | ((ccy & 1) << 1) | (ccz & 1);
        offs[c] = (brick << 4) + (off << 1);
        wts[c] = w;
        sf[tid * 24 + c * 3 + 0] = (float)cx;
        sf[tid * 24 + c * 3 + 1] = (float)cy;
        sf[tid * 24 + c * 3 + 2] = (float)cz;
    }

    // ---- phase B: 8 gathers issued back-to-back ----
    v2f tw[8];
#pragma unroll
    for (int c = 0; c < 8; ++c) {
        tw[c] = *reinterpret_cast<const v2f*>(packed + (size_t)offs[c]);
    }

    // ---- phase C: accumulate ----
    float fv = 0.f, fw = 0.f;
#pragma unroll
    for (int c = 0; c < 8; ++c) {
        const float vm = ((vmask >> c) & 1u) ? 1.f : 0.f;
        fv += tw[c].x * vm * wts[c];
        fw += tw[c].y * vm * wts[c];
    }

    const size_t Ms = (size_t)M;
    out[m] = fv;
    out[33 * Ms + m] = fw;

    // ---- idx flush: lane-contiguous float4 bursts ----
    __syncthreads();
    v4f* __restrict__ dsti =
        reinterpret_cast<v4f*>(out + Ms + (size_t)blockIdx.x * 6144);
#pragma unroll
    for (int k = 0; k < 6; ++k) dsti[k * 256 + tid] = s4[k * 256 + tid];
    __syncthreads();

    // ---- wts: same trick, reusing the buffer ----
    const v4f* wi = reinterpret_cast<const v4f*>(wts);
    s4[tid * 2 + 0] = wi[0];
    s4[tid * 2 + 1] = wi[1];
    __syncthreads();
    v4f* __restrict__ dstw =
        reinterpret_cast<v4f*>(out + 25 * Ms + (size_t)blockIdx.x * 2048);
    dstw[0 * 256 + tid] = s4[0 * 256 + tid];
    dstw[1 * 256 + tid] = s4[1 * 256 + tid];
}

// ---------------- v4 extractor (fallback when M % 256 != 0) ---------------
__global__ __launch_bounds__(256) void extractor_packed(
    const float* __restrict__ points,
    const float* __restrict__ packed,
    float* __restrict__ out,
    int M)
{
    const int m = blockIdx.x * 256 + threadIdx.x;
    if (m >= M) return;

    const size_t p3 = 3ull * (size_t)m;
    const float px = points[p3 + 0];
    const float py = points[p3 + 1];
    const float pz = points[p3 + 2];

    const float fx = floorf(px), fy = floorf(py), fz = floorf(pz);
    const int bx = (int)fx, by = (int)fy, bz = (int)fz;

    const float dxc = fx + 0.5f - px;
    const float dyc = fy + 0.5f - py;
    const float dzc = fz + 0.5f - pz;

    const int nx = (dxc > 0.f) ? 1 : ((dxc < 0.f) ? -1 : 0);
    const int ny = (dyc > 0.f) ? 1 : ((dyc < 0.f) ? -1 : 0);
    const int nz = (dzc > 0.f) ? 1 : ((dzc < 0.f) ? -1 : 0);

    const float ax = fabsf(dxc), ay = fabsf(dyc), az = fabsf(dzc);
    const float axi = 1.f - ax, ayi = 1.f - ay, azi = 1.f - az;

    float fv = 0.f, fw = 0.f;
    float idxf[24];
    float wts[8];

#pragma unroll
    for (int c = 0; c < 8; ++c) {
        const int ox = (c >> 2) & 1;
        const int oy = (c >> 1) & 1;
        const int oz = c & 1;
        const int cx = bx + (ox ? nx : 0);
        const int cy = by + (oy ? ny : 0);
        const int cz = bz + (oz ? nz : 0);
        const float w = (ox ? ax : axi) * (oy ? ay : ayi) * (oz ? az : azi);
        const bool valid = ((unsigned)cx < 256u) & ((unsigned)cy < 256u) & ((unsigned)cz < 256u);
        const int ccx = min(max(cx, 0), 255);
        const int ccy = min(max(cy, 0), 255);
        const int ccz = min(max(cz, 0), 255);
        const int brick = ((ccx >> 1) << 14) | ((ccy >> 1) << 7) | (ccz >> 1);
        const int off = ((ccx & 1) << 2) | ((ccy & 1) << 1) | (ccz & 1);
        const size_t fidx = ((size_t)brick << 4) + (size_t)(off << 1);
        const float vm = valid ? 1.f : 0.f;
        const v2f tw = *reinterpret_cast<const v2f*>(packed + fidx);
        fv += tw.x * vm * w;
        fw += tw.y * vm * w;
        idxf[c * 3 + 0] = (float)cx;
        idxf[c * 3 + 1] = (float)cy;
        idxf[c * 3 + 2] = (float)cz;
        wts[c] = w;
    }

    const size_t Ms = (size_t)M;
    out[m] = fv;
    out[33 * Ms + m] = fw;

    float4* __restrict__ oi = reinterpret_cast<float4*>(out + Ms + (size_t)m * 24);
    const float4* ii = reinterpret_cast<const float4*>(idxf);
#pragma unroll
    for (int i = 0; i < 6; ++i) oi[i] = ii[i];

    float4* __restrict__ ow = reinterpret_cast<float4*>(out + 25 * Ms + (size_t)m * 8);
    const float4* wi = reinterpret_cast<const float4*>(wts);
    ow[0] = wi[0];
    ow[1] = wi[1];
}

// ---------------- v1 fallback: no workspace ---------------------------------
__global__ __launch_bounds__(256) void extractor_kernel(
    const float* __restrict__ points,
    const float* __restrict__ tsdf,
    const float* __restrict__ wvol,
    float* __restrict__ out,
    int M)
{
    const int m = blockIdx.x * 256 + threadIdx.x;
    if (m >= M) return;

    const size_t p3 = 3ull * (size_t)m;
    const float px = points[p3 + 0];
    const float py = points[p3 + 1];
    const float pz = points[p3 + 2];

    const float fx = floorf(px), fy = floorf(py), fz = floorf(pz);
    const int bx = (int)fx, by = (int)fy, bz = (int)fz;

    const float dxc = fx + 0.5f - px;
    const float dyc = fy + 0.5f - py;
    const float dzc = fz + 0.5f - pz;

    const int nx = (dxc > 0.f) ? 1 : ((dxc < 0.f) ? -1 : 0);
    const int ny = (dyc > 0.f) ? 1 : ((dyc < 0.f) ? -1 : 0);
    const int nz = (dzc > 0.f) ? 1 : ((dzc < 0.f) ? -1 : 0);

    const float ax = fabsf(dxc), ay = fabsf(dyc), az = fabsf(dzc);
    const float axi = 1.f - ax, ayi = 1.f - ay, azi = 1.f - az;

    float fv = 0.f, fw = 0.f;
    float idxf[24];
    float wts[8];

#pragma unroll
    for (int c = 0; c < 8; ++c) {
        const int ox = (c >> 2) & 1;
        const int oy = (c >> 1) & 1;
        const int oz = c & 1;
        const int cx = bx + (ox ? nx : 0);
        const int cy = by + (oy ? ny : 0);
        const int cz = bz + (oz ? nz : 0);
        const float w = (ox ? ax : axi) * (oy ? ay : ayi) * (oz ? az : azi);
        const bool valid = ((unsigned)cx < 256u) & ((unsigned)cy < 256u) & ((unsigned)cz < 256u);
        const int ccx = min(max(cx, 0), 255);
        const int ccy = min(max(cy, 0), 255);
        const int ccz = min(max(cz, 0), 255);
        const int flat = (ccx << 16) | (ccy << 8) | ccz;
        const float vm = valid ? 1.f : 0.f;
        const float tv = tsdf[flat] * vm;
        const float wv = wvol[flat] * vm;
        fv += tv * w;
        fw += wv * w;
        idxf[c * 3 + 0] = (float)cx;
        idxf[c * 3 + 1] = (float)cy;
        idxf[c * 3 + 2] = (float)cz;
        wts[c] = w;
    }

    const size_t Ms = (size_t)M;
    out[m] = fv;
    out[33 * Ms + m] = fw;

    float4* __restrict__ oi = reinterpret_cast<float4*>(out + Ms + (size_t)m * 24);
    const float4* ii = reinterpret_cast<const float4*>(idxf);
#pragma unroll
    for (int i = 0; i < 6; ++i) oi[i] = ii[i];

    float4* __restrict__ ow = reinterpret_cast<float4*>(out + 25 * Ms + (size_t)m * 8);
    const float4* wi = reinterpret_cast<const float4*>(wts);
    ow[0] = wi[0];
    ow[1] = wi[1];
}

extern "C" void kernel_launch(void* const* d_in, const int* in_sizes, int n_in,
                              void* d_out, int out_size, void* d_ws, size_t ws_size,
                              hipStream_t stream) {
    const float* points = (const float*)d_in[0];
    const float* tsdf   = (const float*)d_in[1];
    const float* wvol   = (const float*)d_in[2];
    float* out = (float*)d_out;

    const int M = in_sizes[0] / 3;               // B*H*N
    const size_t need_brick = 134217728ull;      // 128 MiB: 128^3 * 64 B

    if (ws_size >= need_brick) {
        float* packed = (float*)d_ws;
        const int nbricks = 128 * 128 * 128;
        pack_brick_kernel<<<nbricks / 256, 256, 0, stream>>>(tsdf, wvol, packed);
        if ((M % 256) == 0) {
            extractor_lds<<<M / 256, 256, 0, stream>>>(points, packed, out, M);
        } else {
            const int blocks = (M + 255) / 256;
            extractor_packed<<<blocks, 256, 0, stream>>>(points, packed, out, M);
        }
    } else {
        const int blocks = (M + 255) / 256;
        extractor_kernel<<<blocks, 256, 0, stream>>>(points, tsdf, wvol, out, M);
    }
}